// Round 3
// baseline (666.505 us; speedup 1.0000x reference)
//
#include <hip/hip_runtime.h>
#include <hip/hip_bf16.h>

#define T_TOK 4096
#define DMODEL 1024
#define DFF 4096
#define NEXP 8
#define ROWS_TOT 8192      // T_TOK * TOPK, fixed
#define ROWS_PAD 8448      // + 256 pad rows for BM=256 tile overrun

typedef __bf16 bf16x8 __attribute__((ext_vector_type(8)));
typedef float f32x4 __attribute__((ext_vector_type(4)));
typedef unsigned short u16;

__device__ __forceinline__ u16 f2bf(float f) {
    __hip_bfloat16 b = __float2bfloat16(f);
    return __builtin_bit_cast(u16, b);
}
__device__ __forceinline__ float bf2f(u16 u) {
    unsigned v = (unsigned)u << 16;
    return __builtin_bit_cast(float, v);
}

// exact-erf GELU via Abramowitz-Stegun 7.1.26 (|eps|<=1.5e-7, far below h's bf16 rounding)
__device__ __forceinline__ float fast_gelu(float v) {
    const float x = v * 0.70710678118654752f;
    const float ax = fabsf(x);
    const float t = 1.f / fmaf(0.3275911f, ax, 1.f);
    float p = fmaf(1.061405429f, t, -1.453152027f);
    p = fmaf(p, t, 1.421413741f);
    p = fmaf(p, t, -0.284496736f);
    p = fmaf(p, t, 0.254829592f);
    p *= t;
    const float e = __expf(-ax * ax);
    float erfv = fmaf(-p, e, 1.f);
    erfv = copysignf(erfv, x);
    return 0.5f * v * (1.f + erfv);
}

// ---------------- router: logits, softmax-top2 gates, expert histogram ----------
__global__ void router_kernel(const float* __restrict__ x, const float* __restrict__ Wr,
                              const float* __restrict__ br, int* __restrict__ top_idx,
                              float* __restrict__ gates, int* __restrict__ counts) {
    const int t = blockIdx.x;
    const int lane = threadIdx.x;
    float part[8];
#pragma unroll
    for (int e = 0; e < 8; ++e) part[e] = 0.f;
#pragma unroll
    for (int j = 0; j < 4; ++j) {
        const int d0 = j * 256 + lane * 4;
        const float4 xv = *(const float4*)(x + (size_t)t * DMODEL + d0);
        const float xs[4] = {xv.x, xv.y, xv.z, xv.w};
#pragma unroll
        for (int i = 0; i < 4; ++i) {
            const float4 w0 = *(const float4*)(Wr + (d0 + i) * 8);
            const float4 w1 = *(const float4*)(Wr + (d0 + i) * 8 + 4);
            part[0] += xs[i] * w0.x; part[1] += xs[i] * w0.y;
            part[2] += xs[i] * w0.z; part[3] += xs[i] * w0.w;
            part[4] += xs[i] * w1.x; part[5] += xs[i] * w1.y;
            part[6] += xs[i] * w1.z; part[7] += xs[i] * w1.w;
        }
    }
#pragma unroll
    for (int m = 32; m > 0; m >>= 1)
#pragma unroll
        for (int e = 0; e < 8; ++e) part[e] += __shfl_xor(part[e], m, 64);
    if (lane == 0) {
        float l[8];
#pragma unroll
        for (int e = 0; e < 8; ++e) l[e] = part[e] + br[e];
        int i1 = 0;
#pragma unroll
        for (int e = 1; e < 8; ++e) if (l[e] > l[i1]) i1 = e;   // first-index tiebreak
        int i2 = (i1 == 0) ? 1 : 0;
#pragma unroll
        for (int e = 0; e < 8; ++e) if (e != i1 && l[e] > l[i2]) i2 = e;
        const float e2 = expf(l[i2] - l[i1]);
        const float inv = 1.f / (1.f + e2);
        top_idx[t * 2 + 0] = i1;  gates[t * 2 + 0] = inv;
        top_idx[t * 2 + 1] = i2;  gates[t * 2 + 1] = e2 * inv;
        atomicAdd(&counts[i1], 1);
        atomicAdd(&counts[i2], 1);
    }
}

// ---------------- exclusive scan over 8 counts -----------------------------------
__global__ void scan_kernel(const int* __restrict__ counts, int* __restrict__ offs,
                            int* __restrict__ cursor) {
    if (threadIdx.x == 0) {
        int s = 0;
        for (int e = 0; e < 8; ++e) { offs[e] = s; cursor[e] = s; s += counts[e]; }
        offs[8] = s;
    }
}

// ---------------- fill sorted row lists + inverse map ----------------------------
__global__ void fill_kernel(const int* __restrict__ top_idx,
                            int* __restrict__ cursor, int* __restrict__ rowtoken,
                            int* __restrict__ slotof) {
    const int t = blockIdx.x * 256 + threadIdx.x;
    if (t >= T_TOK) return;
#pragma unroll
    for (int k = 0; k < 2; ++k) {
        const int e = top_idx[t * 2 + k];
        const int p = atomicAdd(&cursor[e], 1);
        rowtoken[p] = t;
        slotof[t * 2 + k] = p;
    }
}

// ---------------- gather x rows (fp32 -> bf16) into sorted order -----------------
__global__ void gather_kernel(const float* __restrict__ x, const int* __restrict__ rowtoken,
                              u16* __restrict__ Xg) {
    const int p = blockIdx.x;
    const int t = rowtoken[p];
    const int d = threadIdx.x * 4;
    const float4 v = *(const float4*)(x + (size_t)t * DMODEL + d);
    ushort4 o;
    o.x = f2bf(v.x); o.y = f2bf(v.y); o.z = f2bf(v.z); o.w = f2bf(v.w);
    *(ushort4*)(Xg + (size_t)p * DMODEL + d) = o;
}

// ---------------- transpose + fp32->bf16 weight conversion -----------------------
// src [batch][R][C] f32 -> dst [batch][C][R] bf16
__global__ __launch_bounds__(256) void transpose_convert_kernel(
    const float* __restrict__ src, u16* __restrict__ dst, int R, int C) {
    __shared__ float tile[64][65];
    const size_t base = (size_t)blockIdx.z * R * C;
    const int r0 = blockIdx.y * 64, c0 = blockIdx.x * 64;
    const int tr = threadIdx.x >> 4;
    const int tc4 = (threadIdx.x & 15) * 4;
#pragma unroll
    for (int i = 0; i < 4; ++i) {
        const int r = tr + i * 16;
        const float4 v = *(const float4*)(src + base + (size_t)(r0 + r) * C + c0 + tc4);
        tile[r][tc4 + 0] = v.x; tile[r][tc4 + 1] = v.y;
        tile[r][tc4 + 2] = v.z; tile[r][tc4 + 3] = v.w;
    }
    __syncthreads();
#pragma unroll
    for (int i = 0; i < 4; ++i) {
        const int rr = tr + i * 16;
        ushort4 o;
        o.x = f2bf(tile[tc4 + 0][rr]);
        o.y = f2bf(tile[tc4 + 1][rr]);
        o.z = f2bf(tile[tc4 + 2][rr]);
        o.w = f2bf(tile[tc4 + 3][rr]);
        *(ushort4*)(dst + base + (size_t)(c0 + rr) * R + r0 + tc4) = o;
    }
}

// ---------------- grouped GEMM, 256xBN tile, 2-phase double-buffered LDS ---------
// C[p][col] = A[p][:] dot Brow[col][:]  (both K-contiguous), per-expert B/C panels.
// 512 threads = 8 waves as 2(M) x 4(N); per-wave output 128 x (BN/4).
// GELU path: C = gelu(acc + bias[e][col]) -> h. Else: C = acc -> ybuf.
template<int BN, bool GELU>
__global__ __launch_bounds__(512, 2) void gemm2ph_kernel(
    const u16* __restrict__ Amat, const u16* __restrict__ Bmat,
    const float* __restrict__ bias, u16* __restrict__ Cmat,
    const int* __restrict__ offs, const int* __restrict__ counts,
    const int K, const int Ntot) {
    constexpr int NR = BN / 64;          // 16x16 fragments per wave in N
    const int NT = Ntot / BN;
    const int e = blockIdx.x / (32 * NT);
    const int rem = blockIdx.x % (32 * NT);
    const int tm = rem / NT, tn = rem % NT;
    const int cnt = counts[e];
    if (tm * 256 >= cnt) return;
    const int pbase = offs[e] + tm * 256;
    const int pend = offs[e] + cnt;
    const int nbase = tn * BN;
    const size_t wbase = (size_t)e * Ntot * K;

    __shared__ __align__(16) u16 As[2][256 * 64];
    __shared__ __align__(16) u16 Bs[2][BN * 64];

    const int tid = threadIdx.x;
    const int lane = tid & 63, wid = tid >> 6;
    const int wm = (wid >> 2) * 128;
    const int wn = (wid & 3) * (BN / 4);
    const int fr = lane & 15, fg = lane >> 4;

    // staging: 16B chunk c = tid + 512*i -> row (tid>>3)+64*i, col 8*(tid&7)
    const int srow = tid >> 3, scol = (tid & 7) * 8;
    const u16* Aptr = Amat + (size_t)(pbase + srow) * K + scol;
    const u16* Bptr = Bmat + wbase + (size_t)(nbase + srow) * K + scol;

    f32x4 acc[8][NR];
#pragma unroll
    for (int m = 0; m < 8; ++m)
#pragma unroll
        for (int n = 0; n < NR; ++n) acc[m][n] = (f32x4){0.f, 0.f, 0.f, 0.f};

    auto stage = [&](int buf, int ks) {
#pragma unroll
        for (int i = 0; i < 4; ++i)
            __builtin_amdgcn_global_load_lds(
                (const __attribute__((address_space(1))) void*)(Aptr + ks + (size_t)(64 * i) * K),
                (__attribute__((address_space(3))) void*)(&As[buf][(size_t)(tid + 512 * i) * 8]),
                16, 0, 0);
#pragma unroll
        for (int i = 0; i < NR; ++i)
            __builtin_amdgcn_global_load_lds(
                (const __attribute__((address_space(1))) void*)(Bptr + ks + (size_t)(64 * i) * K),
                (__attribute__((address_space(3))) void*)(&Bs[buf][(size_t)(tid + 512 * i) * 8]),
                16, 0, 0);
    };
    auto compute = [&](int buf) {
#pragma unroll
        for (int kc = 0; kc < 2; ++kc) {
            bf16x8 a[8], b[NR];
#pragma unroll
            for (int m = 0; m < 8; ++m)
                a[m] = *(const bf16x8*)(&As[buf][(wm + m * 16 + fr) * 64 + kc * 32 + fg * 8]);
#pragma unroll
            for (int n = 0; n < NR; ++n)
                b[n] = *(const bf16x8*)(&Bs[buf][(wn + n * 16 + fr) * 64 + kc * 32 + fg * 8]);
#pragma unroll
            for (int m = 0; m < 8; ++m)
#pragma unroll
                for (int n = 0; n < NR; ++n)
                    acc[m][n] = __builtin_amdgcn_mfma_f32_16x16x32_bf16(
                        a[m], b[n], acc[m][n], 0, 0, 0);
        }
    };

    stage(0, 0);
    __syncthreads();
    int cur = 0;
    const int nk = K >> 6;
    for (int t = 0; t < nk - 1; ++t) {
        stage(cur ^ 1, (t + 1) << 6);   // loads in flight across this tile's MFMA
        compute(cur);
        __syncthreads();                // implicit vmcnt(0)+lgkmcnt(0): next buf ready
        cur ^= 1;
    }
    compute(cur);

    // epilogue: per-lane bias hoist (NR distinct columns), then store
    float bv[NR];
#pragma unroll
    for (int n = 0; n < NR; ++n)
        bv[n] = GELU ? bias[e * Ntot + nbase + wn + n * 16 + fr] : 0.f;
#pragma unroll
    for (int m = 0; m < 8; ++m) {
#pragma unroll
        for (int r = 0; r < 4; ++r) {
            const int p = pbase + wm + m * 16 + fg * 4 + r;
            if (p >= pend) continue;
#pragma unroll
            for (int n = 0; n < NR; ++n) {
                const int col = nbase + wn + n * 16 + fr;
                float v = acc[m][n][r];
                if (GELU) v = fast_gelu(v + bv[n]);
                Cmat[(size_t)p * Ntot + col] = f2bf(v);
            }
        }
    }
}

// ---------------- combine: out[t] = sum_k g_k * (y[p_k] + b2[e_k]) ---------------
__global__ void combine_kernel(const u16* __restrict__ ybuf, const float* __restrict__ b2,
                               const int* __restrict__ top_idx, const float* __restrict__ gates,
                               const int* __restrict__ slotof, float* __restrict__ out) {
    const int t = blockIdx.x;
    const int d = threadIdx.x * 4;
    const int e0 = top_idx[t * 2 + 0], e1 = top_idx[t * 2 + 1];
    const float g0 = gates[t * 2 + 0], g1 = gates[t * 2 + 1];
    const int p0 = slotof[t * 2 + 0], p1 = slotof[t * 2 + 1];
    const ushort4 ya = *(const ushort4*)(ybuf + (size_t)p0 * DMODEL + d);
    const ushort4 yb = *(const ushort4*)(ybuf + (size_t)p1 * DMODEL + d);
    const float4 ba = *(const float4*)(b2 + e0 * DMODEL + d);
    const float4 bb = *(const float4*)(b2 + e1 * DMODEL + d);
    float4 o;
    o.x = g0 * (bf2f(ya.x) + ba.x) + g1 * (bf2f(yb.x) + bb.x);
    o.y = g0 * (bf2f(ya.y) + ba.y) + g1 * (bf2f(yb.y) + bb.y);
    o.z = g0 * (bf2f(ya.z) + ba.z) + g1 * (bf2f(yb.z) + bb.z);
    o.w = g0 * (bf2f(ya.w) + ba.w) + g1 * (bf2f(yb.w) + bb.w);
    *(float4*)(out + (size_t)t * DMODEL + d) = o;
}

extern "C" void kernel_launch(void* const* d_in, const int* in_sizes, int n_in,
                              void* d_out, int out_size, void* d_ws, size_t ws_size,
                              hipStream_t stream) {
    const float* x  = (const float*)d_in[0];
    const float* Wr = (const float*)d_in[1];
    const float* br = (const float*)d_in[2];
    const float* W1 = (const float*)d_in[3];
    const float* b1 = (const float*)d_in[4];
    const float* W2 = (const float*)d_in[5];
    const float* b2 = (const float*)d_in[6];
    float* out = (float*)d_out;

    // workspace carve (all 16B aligned)
    char* w = (char*)d_ws;
    int*   counts   = (int*)(w + 0);          // 32 B
    int*   cursor   = (int*)(w + 32);         // 32 B
    int*   offs     = (int*)(w + 64);         // 64 B
    int*   top_idx  = (int*)(w + 1024);                   // 32 KB
    float* gates    = (float*)(w + 1024 + 32768);         // 32 KB
    int*   rowtoken = (int*)(w + 1024 + 65536);           // 40 KB reserved
    int*   slotof   = (int*)(w + 1024 + 65536 + 40960);   // 32 KB
    u16*   Xg       = (u16*)(w + 1024 + 65536 + 40960 + 32768);  // ybuf aliases this
    u16*   hbuf     = Xg + (size_t)ROWS_PAD * DMODEL;
    u16*   W1T      = hbuf + (size_t)ROWS_PAD * DFF;
    u16*   W2T      = W1T + (size_t)NEXP * DFF * DMODEL;
    u16*   ybuf     = Xg;   // Xg dead after ffn1; same size [ROWS_PAD][DMODEL]
    const size_t need = (size_t)(1024 + 65536 + 40960 + 32768)
        + (size_t)ROWS_PAD * DMODEL * 2 + (size_t)ROWS_PAD * DFF * 2
        + (size_t)NEXP * DFF * DMODEL * 4;
    if (ws_size < need) return;  // fail loudly (absmax) rather than corrupt memory

    hipMemsetAsync(d_ws, 0, 64, stream);  // counts + cursor

    // weight transpose/convert: W1 [e][1024][4096] -> W1T [e][4096][1024]
    transpose_convert_kernel<<<dim3(64, 16, 8), 256, 0, stream>>>(W1, W1T, DMODEL, DFF);
    // W2 [e][4096][1024] -> W2T [e][1024][4096]
    transpose_convert_kernel<<<dim3(16, 64, 8), 256, 0, stream>>>(W2, W2T, DFF, DMODEL);

    router_kernel<<<T_TOK, 64, 0, stream>>>(x, Wr, br, top_idx, gates, counts);
    scan_kernel<<<1, 64, 0, stream>>>(counts, offs, cursor);
    fill_kernel<<<16, 256, 0, stream>>>(top_idx, cursor, rowtoken, slotof);
    gather_kernel<<<ROWS_TOT, 256, 0, stream>>>(x, rowtoken, Xg);

    // ffn1: h = gelu(Xg @ W1T^T + b1); grid covers worst-case expert imbalance
    gemm2ph_kernel<256, true><<<8 * 32 * (DFF / 256), 512, 0, stream>>>(
        Xg, W1T, b1, hbuf, offs, counts, DMODEL, DFF);
    // ffn2: ybuf = h @ W2T^T; BN=128 keeps >=256 active blocks
    gemm2ph_kernel<128, false><<<8 * 32 * (DMODEL / 128), 512, 0, stream>>>(
        hbuf, W2T, nullptr, ybuf, offs, counts, DFF, DMODEL);
    // combine: one block per token
    combine_kernel<<<T_TOK, 256, 0, stream>>>(ybuf, b2, top_idx, gates, slotof, out);
}

// Round 4
// 552.315 us; speedup vs baseline: 1.2067x; 1.2067x over previous
//
#include <hip/hip_runtime.h>
#include <hip/hip_bf16.h>

#define T_TOK 4096
#define DMODEL 1024
#define DFF 4096
#define NEXP 8
#define ROWS_TOT 8192      // T_TOK * TOPK, fixed
#define ROWS_PAD 8448      // + 256 pad rows for BM=256 tile overrun

typedef __bf16 bf16x8 __attribute__((ext_vector_type(8)));
typedef float f32x4 __attribute__((ext_vector_type(4)));
typedef unsigned short u16;

__device__ __forceinline__ u16 f2bf(float f) {
    __hip_bfloat16 b = __float2bfloat16(f);
    return __builtin_bit_cast(u16, b);
}
__device__ __forceinline__ float bf2f(u16 u) {
    unsigned v = (unsigned)u << 16;
    return __builtin_bit_cast(float, v);
}

// exact-erf GELU via Abramowitz-Stegun 7.1.26 (|eps|<=1.5e-7 << bf16 rounding of h)
__device__ __forceinline__ float fast_gelu(float v) {
    const float x = v * 0.70710678118654752f;
    const float ax = fabsf(x);
    const float t = 1.f / fmaf(0.3275911f, ax, 1.f);
    float p = fmaf(1.061405429f, t, -1.453152027f);
    p = fmaf(p, t, 1.421413741f);
    p = fmaf(p, t, -0.284496736f);
    p = fmaf(p, t, 0.254829592f);
    p *= t;
    const float e = __expf(-ax * ax);
    float erfv = fmaf(-p, e, 1.f);
    erfv = copysignf(erfv, x);
    return 0.5f * v * (1.f + erfv);
}

template<int N> __device__ __forceinline__ void waitcnt_vm() {
    if constexpr (N == 8)      asm volatile("s_waitcnt vmcnt(8)" ::: "memory");
    else if constexpr (N == 6) asm volatile("s_waitcnt vmcnt(6)" ::: "memory");
    else                       asm volatile("s_waitcnt vmcnt(0)" ::: "memory");
}

// ---------------- router: logits, softmax-top2 gates, expert histogram ----------
__global__ void router_kernel(const float* __restrict__ x, const float* __restrict__ Wr,
                              const float* __restrict__ br, int* __restrict__ top_idx,
                              float* __restrict__ gates, int* __restrict__ counts) {
    const int t = blockIdx.x;
    const int lane = threadIdx.x;
    float part[8];
#pragma unroll
    for (int e = 0; e < 8; ++e) part[e] = 0.f;
#pragma unroll
    for (int j = 0; j < 4; ++j) {
        const int d0 = j * 256 + lane * 4;
        const float4 xv = *(const float4*)(x + (size_t)t * DMODEL + d0);
        const float xs[4] = {xv.x, xv.y, xv.z, xv.w};
#pragma unroll
        for (int i = 0; i < 4; ++i) {
            const float4 w0 = *(const float4*)(Wr + (d0 + i) * 8);
            const float4 w1 = *(const float4*)(Wr + (d0 + i) * 8 + 4);
            part[0] += xs[i] * w0.x; part[1] += xs[i] * w0.y;
            part[2] += xs[i] * w0.z; part[3] += xs[i] * w0.w;
            part[4] += xs[i] * w1.x; part[5] += xs[i] * w1.y;
            part[6] += xs[i] * w1.z; part[7] += xs[i] * w1.w;
        }
    }
#pragma unroll
    for (int m = 32; m > 0; m >>= 1)
#pragma unroll
        for (int e = 0; e < 8; ++e) part[e] += __shfl_xor(part[e], m, 64);
    if (lane == 0) {
        float l[8];
#pragma unroll
        for (int e = 0; e < 8; ++e) l[e] = part[e] + br[e];
        int i1 = 0;
#pragma unroll
        for (int e = 1; e < 8; ++e) if (l[e] > l[i1]) i1 = e;   // first-index tiebreak
        int i2 = (i1 == 0) ? 1 : 0;
#pragma unroll
        for (int e = 0; e < 8; ++e) if (e != i1 && l[e] > l[i2]) i2 = e;
        const float e2 = expf(l[i2] - l[i1]);
        const float inv = 1.f / (1.f + e2);
        top_idx[t * 2 + 0] = i1;  gates[t * 2 + 0] = inv;
        top_idx[t * 2 + 1] = i2;  gates[t * 2 + 1] = e2 * inv;
        atomicAdd(&counts[i1], 1);
        atomicAdd(&counts[i2], 1);
    }
}

// ---------------- exclusive scan over 8 counts -----------------------------------
__global__ void scan_kernel(const int* __restrict__ counts, int* __restrict__ offs,
                            int* __restrict__ cursor) {
    if (threadIdx.x == 0) {
        int s = 0;
        for (int e = 0; e < 8; ++e) { offs[e] = s; cursor[e] = s; s += counts[e]; }
        offs[8] = s;
    }
}

// ---------------- fill sorted row lists + inverse map ----------------------------
__global__ void fill_kernel(const int* __restrict__ top_idx,
                            int* __restrict__ cursor, int* __restrict__ rowtoken,
                            int* __restrict__ slotof) {
    const int t = blockIdx.x * 256 + threadIdx.x;
    if (t >= T_TOK) return;
#pragma unroll
    for (int k = 0; k < 2; ++k) {
        const int e = top_idx[t * 2 + k];
        const int p = atomicAdd(&cursor[e], 1);
        rowtoken[p] = t;
        slotof[t * 2 + k] = p;
    }
}

// ---------------- gather x rows (fp32 -> bf16) into sorted order -----------------
__global__ void gather_kernel(const float* __restrict__ x, const int* __restrict__ rowtoken,
                              u16* __restrict__ Xg) {
    const int p = blockIdx.x;
    const int t = rowtoken[p];
    const int d = threadIdx.x * 4;
    const float4 v = *(const float4*)(x + (size_t)t * DMODEL + d);
    ushort4 o;
    o.x = f2bf(v.x); o.y = f2bf(v.y); o.z = f2bf(v.z); o.w = f2bf(v.w);
    *(ushort4*)(Xg + (size_t)p * DMODEL + d) = o;
}

// ---------------- transpose + fp32->bf16 weight conversion -----------------------
// src [batch][R][C] f32 -> dst [batch][C][R] bf16
__global__ __launch_bounds__(256) void transpose_convert_kernel(
    const float* __restrict__ src, u16* __restrict__ dst, int R, int C) {
    __shared__ float tile[64][65];
    const size_t base = (size_t)blockIdx.z * R * C;
    const int r0 = blockIdx.y * 64, c0 = blockIdx.x * 64;
    const int tr = threadIdx.x >> 4;
    const int tc4 = (threadIdx.x & 15) * 4;
#pragma unroll
    for (int i = 0; i < 4; ++i) {
        const int r = tr + i * 16;
        const float4 v = *(const float4*)(src + base + (size_t)(r0 + r) * C + c0 + tc4);
        tile[r][tc4 + 0] = v.x; tile[r][tc4 + 1] = v.y;
        tile[r][tc4 + 2] = v.z; tile[r][tc4 + 3] = v.w;
    }
    __syncthreads();
#pragma unroll
    for (int i = 0; i < 4; ++i) {
        const int rr = tr + i * 16;
        ushort4 o;
        o.x = f2bf(tile[tc4 + 0][rr]);
        o.y = f2bf(tile[tc4 + 1][rr]);
        o.z = f2bf(tile[tc4 + 2][rr]);
        o.w = f2bf(tile[tc4 + 3][rr]);
        *(ushort4*)(dst + base + (size_t)(c0 + rr) * R + r0 + tc4) = o;
    }
}

// ---------------- grouped GEMM, BMx256 tile, counted-vmcnt double-buffer ---------
// C[p][col] = A[p][:] dot Brow[col][:] (both K-contiguous), per-expert B/C panels.
// 512 threads = 8 waves as 2(M) x 4(N); per-wave output (BM/2) x 64.
// T2 XOR-swizzle applied both-sides (pre-swizzled global source col + swizzled
// ds_read col; involution within each 128B LDS row).
// K-loop: raw s_barrier + s_waitcnt vmcnt(LOADS) -- next tile's loads stay in
// flight across barriers (T4). setprio around MFMA cluster (T5).
template<int BM, bool GELU>
__global__ __launch_bounds__(512, 2) void gemm_db_kernel(
    const u16* __restrict__ Amat, const u16* __restrict__ Bmat,
    const float* __restrict__ bias, u16* __restrict__ Cmat,
    const int* __restrict__ offs, const int* __restrict__ counts,
    const int K, const int Ntot) {
    constexpr int MR = BM / 32;      // 16-row frags per wave in M
    constexpr int NR = 4;            // 16-col frags per wave in N (BN=256)
    constexpr int AI = BM / 64;      // gload_lds instrs per A-stage
    constexpr int LOADS = AI + 4;    // per-wave outstanding loads per stage
    const int MT = 8192 / BM;
    const int NT = Ntot >> 8;
    const int e = blockIdx.x / (MT * NT);
    const int rem = blockIdx.x % (MT * NT);
    const int tm = rem / NT, tn = rem % NT;
    const int cnt = counts[e];
    if (tm * BM >= cnt) return;
    const int pbase = offs[e] + tm * BM;
    const int pend = offs[e] + cnt;
    const int nbase = tn * 256;
    const size_t wbase = (size_t)e * Ntot * K;

    __shared__ __align__(16) u16 As[2][BM * 64];
    __shared__ __align__(16) u16 Bs[2][256 * 64];

    const int tid = threadIdx.x;
    const int lane = tid & 63, wid = tid >> 6;
    const int wm = (wid >> 2) * (BM / 2);
    const int wn = (wid & 3) * 64;
    const int fr = lane & 15, fg = lane >> 4;
    const int rsw = (fr & 7) * 8;            // read-side XOR (elements)

    // stage: 16B chunk c = tid + 512*i -> LDS row (tid>>3)+64*i; global col
    // pre-swizzled so that LDS-linear write lands swizzled data (rule #21).
    const int srow = tid >> 3;
    const int scol = 8 * ((tid & 7) ^ ((tid >> 3) & 7));
    const u16* Aptr = Amat + (size_t)(pbase + srow) * K + scol;
    const u16* Bptr = Bmat + wbase + (size_t)(nbase + srow) * K + scol;

    f32x4 acc[MR][NR];
#pragma unroll
    for (int m = 0; m < MR; ++m)
#pragma unroll
        for (int n = 0; n < NR; ++n) acc[m][n] = (f32x4){0.f, 0.f, 0.f, 0.f};

    auto stage = [&](int buf, int ks) {
#pragma unroll
        for (int i = 0; i < AI; ++i)
            __builtin_amdgcn_global_load_lds(
                (const __attribute__((address_space(1))) void*)(Aptr + ks + (size_t)(64 * i) * K),
                (__attribute__((address_space(3))) void*)(&As[buf][(size_t)(tid + 512 * i) * 8]),
                16, 0, 0);
#pragma unroll
        for (int i = 0; i < 4; ++i)
            __builtin_amdgcn_global_load_lds(
                (const __attribute__((address_space(1))) void*)(Bptr + ks + (size_t)(64 * i) * K),
                (__attribute__((address_space(3))) void*)(&Bs[buf][(size_t)(tid + 512 * i) * 8]),
                16, 0, 0);
    };
    auto compute = [&](int buf) {
#pragma unroll
        for (int kc = 0; kc < 2; ++kc) {
            const int col = (kc * 32 + fg * 8) ^ rsw;
            bf16x8 a[MR], b[NR];
#pragma unroll
            for (int m = 0; m < MR; ++m)
                a[m] = *(const bf16x8*)(&As[buf][(wm + m * 16 + fr) * 64 + col]);
#pragma unroll
            for (int n = 0; n < NR; ++n)
                b[n] = *(const bf16x8*)(&Bs[buf][(wn + n * 16 + fr) * 64 + col]);
            __builtin_amdgcn_s_setprio(1);
#pragma unroll
            for (int m = 0; m < MR; ++m)
#pragma unroll
                for (int n = 0; n < NR; ++n)
                    acc[m][n] = __builtin_amdgcn_mfma_f32_16x16x32_bf16(
                        a[m], b[n], acc[m][n], 0, 0, 0);
            __builtin_amdgcn_s_setprio(0);
        }
    };

    stage(0, 0);
    stage(1, 64);
    const int nk = K >> 6;
    for (int t = 0; t < nk; ++t) {
        // own-wave tile-t loads done; barrier publishes all waves' writes
        if (t < nk - 1) waitcnt_vm<LOADS>(); else waitcnt_vm<0>();
        __builtin_amdgcn_s_barrier();
        asm volatile("" ::: "memory");   // ds_reads may not hoist above barrier
        compute(t & 1);
        if (t < nk - 2) {
            asm volatile("" ::: "memory");   // ds_reads may not sink below barrier
            __builtin_amdgcn_s_barrier();    // all waves done reading buf[t&1]
            stage(t & 1, (t + 2) << 6);      // overwrite with tile t+2 (stays in flight)
        }
    }

    // epilogue: per-lane bias hoist (NR distinct columns), then store
    float bv[NR];
#pragma unroll
    for (int n = 0; n < NR; ++n)
        bv[n] = GELU ? bias[e * Ntot + nbase + wn + n * 16 + fr] : 0.f;
#pragma unroll
    for (int m = 0; m < MR; ++m) {
#pragma unroll
        for (int r = 0; r < 4; ++r) {
            const int p = pbase + wm + m * 16 + fg * 4 + r;
            if (p >= pend) continue;
#pragma unroll
            for (int n = 0; n < NR; ++n) {
                const int col = nbase + wn + n * 16 + fr;
                float v = acc[m][n][r];
                if (GELU) v = fast_gelu(v + bv[n]);
                Cmat[(size_t)p * Ntot + col] = f2bf(v);
            }
        }
    }
}

// ---------------- combine: out[t] = sum_k g_k * (y[p_k] + b2[e_k]) ---------------
__global__ void combine_kernel(const u16* __restrict__ ybuf, const float* __restrict__ b2,
                               const int* __restrict__ top_idx, const float* __restrict__ gates,
                               const int* __restrict__ slotof, float* __restrict__ out) {
    const int t = blockIdx.x;
    const int d = threadIdx.x * 4;
    const int e0 = top_idx[t * 2 + 0], e1 = top_idx[t * 2 + 1];
    const float g0 = gates[t * 2 + 0], g1 = gates[t * 2 + 1];
    const int p0 = slotof[t * 2 + 0], p1 = slotof[t * 2 + 1];
    const ushort4 ya = *(const ushort4*)(ybuf + (size_t)p0 * DMODEL + d);
    const ushort4 yb = *(const ushort4*)(ybuf + (size_t)p1 * DMODEL + d);
    const float4 ba = *(const float4*)(b2 + e0 * DMODEL + d);
    const float4 bb = *(const float4*)(b2 + e1 * DMODEL + d);
    float4 o;
    o.x = g0 * (bf2f(ya.x) + ba.x) + g1 * (bf2f(yb.x) + bb.x);
    o.y = g0 * (bf2f(ya.y) + ba.y) + g1 * (bf2f(yb.y) + bb.y);
    o.z = g0 * (bf2f(ya.z) + ba.z) + g1 * (bf2f(yb.z) + bb.z);
    o.w = g0 * (bf2f(ya.w) + ba.w) + g1 * (bf2f(yb.w) + bb.w);
    *(float4*)(out + (size_t)t * DMODEL + d) = o;
}

extern "C" void kernel_launch(void* const* d_in, const int* in_sizes, int n_in,
                              void* d_out, int out_size, void* d_ws, size_t ws_size,
                              hipStream_t stream) {
    const float* x  = (const float*)d_in[0];
    const float* Wr = (const float*)d_in[1];
    const float* br = (const float*)d_in[2];
    const float* W1 = (const float*)d_in[3];
    const float* b1 = (const float*)d_in[4];
    const float* W2 = (const float*)d_in[5];
    const float* b2 = (const float*)d_in[6];
    float* out = (float*)d_out;

    // workspace carve (all 16B aligned)
    char* w = (char*)d_ws;
    int*   counts   = (int*)(w + 0);          // 32 B
    int*   cursor   = (int*)(w + 32);         // 32 B
    int*   offs     = (int*)(w + 64);         // 64 B
    int*   top_idx  = (int*)(w + 1024);                   // 32 KB
    float* gates    = (float*)(w + 1024 + 32768);         // 32 KB
    int*   rowtoken = (int*)(w + 1024 + 65536);           // 40 KB reserved
    int*   slotof   = (int*)(w + 1024 + 65536 + 40960);   // 32 KB
    u16*   Xg       = (u16*)(w + 1024 + 65536 + 40960 + 32768);  // ybuf aliases this
    u16*   hbuf     = Xg + (size_t)ROWS_PAD * DMODEL;
    u16*   W1T      = hbuf + (size_t)ROWS_PAD * DFF;
    u16*   W2T      = W1T + (size_t)NEXP * DFF * DMODEL;
    u16*   ybuf     = Xg;   // Xg dead after ffn1; same size [ROWS_PAD][DMODEL]
    const size_t need = (size_t)(1024 + 65536 + 40960 + 32768)
        + (size_t)ROWS_PAD * DMODEL * 2 + (size_t)ROWS_PAD * DFF * 2
        + (size_t)NEXP * DFF * DMODEL * 4;
    if (ws_size < need) return;  // fail loudly (absmax) rather than corrupt memory

    hipMemsetAsync(d_ws, 0, 64, stream);  // counts + cursor

    // weight transpose/convert: W1 [e][1024][4096] -> W1T [e][4096][1024]
    transpose_convert_kernel<<<dim3(64, 16, 8), 256, 0, stream>>>(W1, W1T, DMODEL, DFF);
    // W2 [e][4096][1024] -> W2T [e][1024][4096]
    transpose_convert_kernel<<<dim3(16, 64, 8), 256, 0, stream>>>(W2, W2T, DFF, DMODEL);

    router_kernel<<<T_TOK, 64, 0, stream>>>(x, Wr, br, top_idx, gates, counts);
    scan_kernel<<<1, 64, 0, stream>>>(counts, offs, cursor);
    fill_kernel<<<16, 256, 0, stream>>>(top_idx, cursor, rowtoken, slotof);
    gather_kernel<<<ROWS_TOT, 256, 0, stream>>>(x, rowtoken, Xg);

    // ffn1: h = gelu(Xg @ W1T^T + b1); BM=256, worst-case grid, early-exit
    gemm_db_kernel<256, true><<<8 * 32 * 16, 512, 0, stream>>>(
        Xg, W1T, b1, hbuf, offs, counts, DMODEL, DFF);
    // ffn2: ybuf = h @ W2T^T; BM=128 -> ~256 active blocks
    gemm_db_kernel<128, false><<<8 * 64 * 4, 512, 0, stream>>>(
        hbuf, W2T, nullptr, ybuf, offs, counts, DFF, DMODEL);
    // combine: one block per token
    combine_kernel<<<T_TOK, 256, 0, stream>>>(ybuf, b2, top_idx, gates, slotof, out);
}

// Round 5
// 487.707 us; speedup vs baseline: 1.3666x; 1.1325x over previous
//
#include <hip/hip_runtime.h>
#include <hip/hip_bf16.h>

#define T_TOK 4096
#define DMODEL 1024
#define DFF 4096
#define NEXP 8
#define ROWS_TOT 8192      // T_TOK * TOPK, fixed
#define ROWS_PAD 8448      // + 256 pad rows for BM=256 tile overrun

typedef __bf16 bf16x8 __attribute__((ext_vector_type(8)));
typedef float f32x4 __attribute__((ext_vector_type(4)));
typedef unsigned short u16;

__device__ __forceinline__ u16 f2bf(float f) {
    __hip_bfloat16 b = __float2bfloat16(f);
    return __builtin_bit_cast(u16, b);
}
__device__ __forceinline__ float bf2f(u16 u) {
    unsigned v = (unsigned)u << 16;
    return __builtin_bit_cast(float, v);
}

// exact-erf GELU via Abramowitz-Stegun 7.1.26 (|eps|<=1.5e-7 << bf16 rounding of h)
__device__ __forceinline__ float fast_gelu(float v) {
    const float x = v * 0.70710678118654752f;
    const float ax = fabsf(x);
    const float t = 1.f / fmaf(0.3275911f, ax, 1.f);
    float p = fmaf(1.061405429f, t, -1.453152027f);
    p = fmaf(p, t, 1.421413741f);
    p = fmaf(p, t, -0.284496736f);
    p = fmaf(p, t, 0.254829592f);
    p *= t;
    const float e = __expf(-ax * ax);
    float erfv = fmaf(-p, e, 1.f);
    erfv = copysignf(erfv, x);
    return 0.5f * v * (1.f + erfv);
}

template<int N> __device__ __forceinline__ void waitcnt_vm() {
    if constexpr (N == 8)      asm volatile("s_waitcnt vmcnt(8)" ::: "memory");
    else if constexpr (N == 6) asm volatile("s_waitcnt vmcnt(6)" ::: "memory");
    else                       asm volatile("s_waitcnt vmcnt(0)" ::: "memory");
}

// ---------------- router: logits, softmax-top2 gates, expert histogram ----------
__global__ void router_kernel(const float* __restrict__ x, const float* __restrict__ Wr,
                              const float* __restrict__ br, int* __restrict__ top_idx,
                              float* __restrict__ gates, int* __restrict__ counts) {
    const int t = blockIdx.x;
    const int lane = threadIdx.x;
    float part[8];
#pragma unroll
    for (int e = 0; e < 8; ++e) part[e] = 0.f;
#pragma unroll
    for (int j = 0; j < 4; ++j) {
        const int d0 = j * 256 + lane * 4;
        const float4 xv = *(const float4*)(x + (size_t)t * DMODEL + d0);
        const float xs[4] = {xv.x, xv.y, xv.z, xv.w};
#pragma unroll
        for (int i = 0; i < 4; ++i) {
            const float4 w0 = *(const float4*)(Wr + (d0 + i) * 8);
            const float4 w1 = *(const float4*)(Wr + (d0 + i) * 8 + 4);
            part[0] += xs[i] * w0.x; part[1] += xs[i] * w0.y;
            part[2] += xs[i] * w0.z; part[3] += xs[i] * w0.w;
            part[4] += xs[i] * w1.x; part[5] += xs[i] * w1.y;
            part[6] += xs[i] * w1.z; part[7] += xs[i] * w1.w;
        }
    }
#pragma unroll
    for (int m = 32; m > 0; m >>= 1)
#pragma unroll
        for (int e = 0; e < 8; ++e) part[e] += __shfl_xor(part[e], m, 64);
    if (lane == 0) {
        float l[8];
#pragma unroll
        for (int e = 0; e < 8; ++e) l[e] = part[e] + br[e];
        int i1 = 0;
#pragma unroll
        for (int e = 1; e < 8; ++e) if (l[e] > l[i1]) i1 = e;   // first-index tiebreak
        int i2 = (i1 == 0) ? 1 : 0;
#pragma unroll
        for (int e = 0; e < 8; ++e) if (e != i1 && l[e] > l[i2]) i2 = e;
        const float e2 = expf(l[i2] - l[i1]);
        const float inv = 1.f / (1.f + e2);
        top_idx[t * 2 + 0] = i1;  gates[t * 2 + 0] = inv;
        top_idx[t * 2 + 1] = i2;  gates[t * 2 + 1] = e2 * inv;
        atomicAdd(&counts[i1], 1);
        atomicAdd(&counts[i2], 1);
    }
}

// ---------------- fused scan + fill (single block; LDS cursors) ------------------
__global__ void fillscan_kernel(const int* __restrict__ top_idx, const int* __restrict__ counts,
                                int* __restrict__ offs, int* __restrict__ rowtoken,
                                int* __restrict__ slotof) {
    __shared__ int lcur[8];
    if (threadIdx.x == 0) {
        int s = 0;
        for (int e = 0; e < 8; ++e) { offs[e] = s; lcur[e] = s; s += counts[e]; }
        offs[8] = s;
    }
    __syncthreads();
    for (int t = threadIdx.x; t < T_TOK; t += 1024) {
#pragma unroll
        for (int k = 0; k < 2; ++k) {
            const int e = top_idx[t * 2 + k];
            const int p = atomicAdd(&lcur[e], 1);
            rowtoken[p] = t;
            slotof[t * 2 + k] = p;
        }
    }
}

// ---------------- gather x rows (fp32 -> bf16) into sorted order -----------------
__global__ void gather_kernel(const float* __restrict__ x, const int* __restrict__ rowtoken,
                              u16* __restrict__ Xg) {
    const int p = blockIdx.x;
    const int t = rowtoken[p];
    const int d = threadIdx.x * 4;
    const float4 v = *(const float4*)(x + (size_t)t * DMODEL + d);
    ushort4 o;
    o.x = f2bf(v.x); o.y = f2bf(v.y); o.z = f2bf(v.z); o.w = f2bf(v.w);
    *(ushort4*)(Xg + (size_t)p * DMODEL + d) = o;
}

// ---------------- transpose + fp32->bf16 weight conversion -----------------------
// src [batch][R][C] f32 -> dst [batch][C][R] bf16
__global__ __launch_bounds__(256) void transpose_convert_kernel(
    const float* __restrict__ src, u16* __restrict__ dst, int R, int C) {
    __shared__ float tile[64][65];
    const size_t base = (size_t)blockIdx.z * R * C;
    const int r0 = blockIdx.y * 64, c0 = blockIdx.x * 64;
    const int tr = threadIdx.x >> 4;
    const int tc4 = (threadIdx.x & 15) * 4;
#pragma unroll
    for (int i = 0; i < 4; ++i) {
        const int r = tr + i * 16;
        const float4 v = *(const float4*)(src + base + (size_t)(r0 + r) * C + c0 + tc4);
        tile[r][tc4 + 0] = v.x; tile[r][tc4 + 1] = v.y;
        tile[r][tc4 + 2] = v.z; tile[r][tc4 + 3] = v.w;
    }
    __syncthreads();
#pragma unroll
    for (int i = 0; i < 4; ++i) {
        const int rr = tr + i * 16;
        ushort4 o;
        o.x = f2bf(tile[tc4 + 0][rr]);
        o.y = f2bf(tile[tc4 + 1][rr]);
        o.z = f2bf(tile[tc4 + 2][rr]);
        o.w = f2bf(tile[tc4 + 3][rr]);
        *(ushort4*)(dst + base + (size_t)(c0 + rr) * R + r0 + tc4) = o;
    }
}

// ---------------- grouped GEMM, 256x256 tile, counted-vmcnt double-buffer --------
// C[p][col] = A[p][kbeg..kend) dot B[col][.] (both K-contiguous), per-expert B.
// 512 threads = 8 waves as 2(M) x 4(N); per-wave output 128x64 (MR=8, NR=4:
// 2.67 MFMA per ds_read_b128). Optional split-K (KH blocks per tile) writing
// independent partial buffers C0/C1 (combined later; no atomics, no races).
// Sync skeleton identical to round-4 verified kernel: per K-step
//   waitcnt vmcnt(8) -> s_barrier -> compute -> s_barrier -> stage(t+2).
// T2 both-sides XOR swizzle (zero bank conflicts measured), T5 setprio.
template<bool GELU>
__global__ __launch_bounds__(512, 2) void gemm256_kernel(
    const u16* __restrict__ Amat, const int lda,
    const u16* __restrict__ Bmat, const int ldb,
    const float* __restrict__ bias,
    u16* __restrict__ C0, u16* __restrict__ C1, const int ldc,
    const int* __restrict__ offs, const int* __restrict__ counts,
    const int Ntot, const int NT, const int KH, const int ksteps) {
    int bid = blockIdx.x;
    const int kh = bid % KH;  bid /= KH;
    const int tn = bid % NT;  bid /= NT;
    const int tm = bid & 31;  const int e = bid >> 5;   // MTmax = 32
    const int cnt = counts[e];
    if (tm * 256 >= cnt) return;
    const int pbase = offs[e] + tm * 256;
    const int pend  = offs[e] + cnt;
    const int nbase = tn * 256;
    const int k0 = kh * (ksteps << 6);
    u16* __restrict__ Cmat = kh ? C1 : C0;

    __shared__ __align__(16) u16 As[2][256 * 64];
    __shared__ __align__(16) u16 Bs[2][256 * 64];

    const int tid = threadIdx.x;
    const int lane = tid & 63, wid = tid >> 6;
    const int wm = (wid >> 2) * 128;
    const int wn = (wid & 3) * 64;
    const int fr = lane & 15, fg = lane >> 4;
    const int rsw = (fr & 7) * 8;            // read-side XOR (elements)

    // stage: 16B chunk c = tid + 512*i -> LDS row (tid>>3)+64*i; global col
    // pre-swizzled so the LDS-linear write lands swizzled data (rule #21).
    const int srow = tid >> 3;
    const int scol = 8 * ((tid & 7) ^ ((tid >> 3) & 7));
    const u16* Aptr = Amat + (size_t)(pbase + srow) * lda + k0 + scol;
    const u16* Bptr = Bmat + (size_t)e * Ntot * ldb
                           + (size_t)(nbase + srow) * ldb + k0 + scol;

    f32x4 acc[8][4];
#pragma unroll
    for (int m = 0; m < 8; ++m)
#pragma unroll
        for (int n = 0; n < 4; ++n) acc[m][n] = (f32x4){0.f, 0.f, 0.f, 0.f};

    auto stage = [&](int buf, int ks) {
#pragma unroll
        for (int i = 0; i < 4; ++i)
            __builtin_amdgcn_global_load_lds(
                (const __attribute__((address_space(1))) void*)(Aptr + ks + (size_t)(64 * i) * lda),
                (__attribute__((address_space(3))) void*)(&As[buf][(size_t)(tid + 512 * i) * 8]),
                16, 0, 0);
#pragma unroll
        for (int i = 0; i < 4; ++i)
            __builtin_amdgcn_global_load_lds(
                (const __attribute__((address_space(1))) void*)(Bptr + ks + (size_t)(64 * i) * ldb),
                (__attribute__((address_space(3))) void*)(&Bs[buf][(size_t)(tid + 512 * i) * 8]),
                16, 0, 0);
    };
    auto compute = [&](int buf) {
#pragma unroll
        for (int kc = 0; kc < 2; ++kc) {
            const int col = (kc * 32 + fg * 8) ^ rsw;
            bf16x8 a[8], b[4];
#pragma unroll
            for (int m = 0; m < 8; ++m)
                a[m] = *(const bf16x8*)(&As[buf][(wm + m * 16 + fr) * 64 + col]);
#pragma unroll
            for (int n = 0; n < 4; ++n)
                b[n] = *(const bf16x8*)(&Bs[buf][(wn + n * 16 + fr) * 64 + col]);
            __builtin_amdgcn_s_setprio(1);
#pragma unroll
            for (int m = 0; m < 8; ++m)
#pragma unroll
                for (int n = 0; n < 4; ++n)
                    acc[m][n] = __builtin_amdgcn_mfma_f32_16x16x32_bf16(
                        a[m], b[n], acc[m][n], 0, 0, 0);
            __builtin_amdgcn_s_setprio(0);
        }
    };

    stage(0, 0);
    stage(1, 64);
    const int nk = ksteps;
    for (int t = 0; t < nk; ++t) {
        // own-wave tile-t loads done; barrier publishes all waves' writes
        if (t < nk - 1) waitcnt_vm<8>(); else waitcnt_vm<0>();
        __builtin_amdgcn_s_barrier();
        asm volatile("" ::: "memory");   // ds_reads may not hoist above barrier
        compute(t & 1);
        if (t < nk - 2) {
            asm volatile("" ::: "memory");   // ds_reads may not sink below barrier
            __builtin_amdgcn_s_barrier();    // all waves done reading buf[t&1]
            stage(t & 1, (t + 2) << 6);      // overwrite with tile t+2 (stays in flight)
        }
    }

    // epilogue: per-lane bias hoist (4 distinct columns), then store
    float bv[4];
#pragma unroll
    for (int n = 0; n < 4; ++n)
        bv[n] = GELU ? bias[e * Ntot + nbase + wn + n * 16 + fr] : 0.f;
#pragma unroll
    for (int m = 0; m < 8; ++m) {
#pragma unroll
        for (int r = 0; r < 4; ++r) {
            const int p = pbase + wm + m * 16 + fg * 4 + r;
            if (p >= pend) continue;
#pragma unroll
            for (int n = 0; n < 4; ++n) {
                const int col = nbase + wn + n * 16 + fr;
                float v = acc[m][n][r];
                if (GELU) v = fast_gelu(v + bv[n]);
                Cmat[(size_t)p * ldc + col] = f2bf(v);
            }
        }
    }
}

// ------- combine: out[t] = sum_k g_k * (y0[p_k] + y1[p_k] + b2[e_k]) -------------
__global__ void combine_kernel(const u16* __restrict__ ybuf0, const u16* __restrict__ ybuf1,
                               const float* __restrict__ b2,
                               const int* __restrict__ top_idx, const float* __restrict__ gates,
                               const int* __restrict__ slotof, float* __restrict__ out) {
    const int t = blockIdx.x;
    const int d = threadIdx.x * 4;
    const int e0 = top_idx[t * 2 + 0], e1 = top_idx[t * 2 + 1];
    const float g0 = gates[t * 2 + 0], g1 = gates[t * 2 + 1];
    const int p0 = slotof[t * 2 + 0], p1 = slotof[t * 2 + 1];
    const ushort4 ya0 = *(const ushort4*)(ybuf0 + (size_t)p0 * DMODEL + d);
    const ushort4 ya1 = *(const ushort4*)(ybuf1 + (size_t)p0 * DMODEL + d);
    const ushort4 yb0 = *(const ushort4*)(ybuf0 + (size_t)p1 * DMODEL + d);
    const ushort4 yb1 = *(const ushort4*)(ybuf1 + (size_t)p1 * DMODEL + d);
    const float4 ba = *(const float4*)(b2 + e0 * DMODEL + d);
    const float4 bb = *(const float4*)(b2 + e1 * DMODEL + d);
    float4 o;
    o.x = g0 * (bf2f(ya0.x) + bf2f(ya1.x) + ba.x) + g1 * (bf2f(yb0.x) + bf2f(yb1.x) + bb.x);
    o.y = g0 * (bf2f(ya0.y) + bf2f(ya1.y) + ba.y) + g1 * (bf2f(yb0.y) + bf2f(yb1.y) + bb.y);
    o.z = g0 * (bf2f(ya0.z) + bf2f(ya1.z) + ba.z) + g1 * (bf2f(yb0.z) + bf2f(yb1.z) + bb.z);
    o.w = g0 * (bf2f(ya0.w) + bf2f(ya1.w) + ba.w) + g1 * (bf2f(yb0.w) + bf2f(yb1.w) + bb.w);
    *(float4*)(out + (size_t)t * DMODEL + d) = o;
}

extern "C" void kernel_launch(void* const* d_in, const int* in_sizes, int n_in,
                              void* d_out, int out_size, void* d_ws, size_t ws_size,
                              hipStream_t stream) {
    const float* x  = (const float*)d_in[0];
    const float* Wr = (const float*)d_in[1];
    const float* br = (const float*)d_in[2];
    const float* W1 = (const float*)d_in[3];
    const float* b1 = (const float*)d_in[4];
    const float* W2 = (const float*)d_in[5];
    const float* b2 = (const float*)d_in[6];
    float* out = (float*)d_out;

    // workspace carve (all 16B aligned)
    char* w = (char*)d_ws;
    int*   counts   = (int*)(w + 0);          // 32 B
    int*   offs     = (int*)(w + 64);         // 64 B
    int*   top_idx  = (int*)(w + 1024);                   // 32 KB
    float* gates    = (float*)(w + 1024 + 32768);         // 32 KB
    int*   rowtoken = (int*)(w + 1024 + 65536);           // 40 KB reserved
    int*   slotof   = (int*)(w + 1024 + 65536 + 40960);   // 32 KB
    u16*   Xg       = (u16*)(w + 1024 + 65536 + 40960 + 32768);
    u16*   hbuf     = Xg + (size_t)ROWS_PAD * DMODEL;
    u16*   W1T      = hbuf + (size_t)ROWS_PAD * DFF;
    u16*   W2T      = W1T + (size_t)NEXP * DFF * DMODEL;
    u16*   ybuf0    = Xg;    // Xg dead after ffn1  [ROWS_PAD][DMODEL]
    u16*   ybuf1    = W1T;   // W1T dead after ffn1 [ROWS_PAD][DMODEL] (fits: 17MB < 64MB)
    const size_t need = (size_t)(1024 + 65536 + 40960 + 32768)
        + (size_t)ROWS_PAD * DMODEL * 2 + (size_t)ROWS_PAD * DFF * 2
        + (size_t)NEXP * DFF * DMODEL * 4;
    if (ws_size < need) return;  // fail loudly (absmax) rather than corrupt memory

    hipMemsetAsync(d_ws, 0, 64, stream);  // counts

    // weight transpose/convert: W1 [e][1024][4096] -> W1T [e][4096][1024]
    transpose_convert_kernel<<<dim3(64, 16, 8), 256, 0, stream>>>(W1, W1T, DMODEL, DFF);
    // W2 [e][4096][1024] -> W2T [e][1024][4096]
    transpose_convert_kernel<<<dim3(16, 64, 8), 256, 0, stream>>>(W2, W2T, DFF, DMODEL);

    router_kernel<<<T_TOK, 64, 0, stream>>>(x, Wr, br, top_idx, gates, counts);
    fillscan_kernel<<<1, 1024, 0, stream>>>(top_idx, counts, offs, rowtoken, slotof);
    gather_kernel<<<ROWS_TOT, 256, 0, stream>>>(x, rowtoken, Xg);

    // ffn1: h = gelu(Xg @ W1T^T + b1); 256x256 tile, K=1024 (16 steps), KH=1
    gemm256_kernel<true><<<8 * 32 * 16, 512, 0, stream>>>(
        Xg, DMODEL, W1T, DMODEL, b1, hbuf, nullptr, DFF,
        offs, counts, DFF, 16, 1, 16);
    // ffn2: y = h @ W2T^T; 256x256 tile, split-K=2 (2048 each, 32 steps)
    gemm256_kernel<false><<<8 * 32 * 4 * 2, 512, 0, stream>>>(
        hbuf, DFF, W2T, DFF, nullptr, ybuf0, ybuf1, DMODEL,
        offs, counts, DMODEL, 4, 2, 32);
    // combine: one block per token
    combine_kernel<<<T_TOK, 256, 0, stream>>>(ybuf0, ybuf1, b2, top_idx, gates, slotof, out);
}

// Round 6
// 468.813 us; speedup vs baseline: 1.4217x; 1.0403x over previous
//
#include <hip/hip_runtime.h>
#include <hip/hip_bf16.h>

#define T_TOK 4096
#define DMODEL 1024
#define DFF 4096
#define NEXP 8
#define ROWS_TOT 8192      // T_TOK * TOPK, fixed
#define ROWS_PAD 8448      // + 256 pad rows for BM=256 tile overrun

typedef __bf16 bf16x8 __attribute__((ext_vector_type(8)));
typedef float f32x4 __attribute__((ext_vector_type(4)));
typedef unsigned short u16;

__device__ __forceinline__ u16 f2bf(float f) {
    __hip_bfloat16 b = __float2bfloat16(f);
    return __builtin_bit_cast(u16, b);
}
__device__ __forceinline__ float bf2f(u16 u) {
    unsigned v = (unsigned)u << 16;
    return __builtin_bit_cast(float, v);
}

// exact-erf GELU via Abramowitz-Stegun 7.1.26 (|eps|<=1.5e-7 << bf16 rounding of h)
__device__ __forceinline__ float fast_gelu(float v) {
    const float x = v * 0.70710678118654752f;
    const float ax = fabsf(x);
    const float t = 1.f / fmaf(0.3275911f, ax, 1.f);
    float p = fmaf(1.061405429f, t, -1.453152027f);
    p = fmaf(p, t, 1.421413741f);
    p = fmaf(p, t, -0.284496736f);
    p = fmaf(p, t, 0.254829592f);
    p *= t;
    const float e = __expf(-ax * ax);
    float erfv = fmaf(-p, e, 1.f);
    erfv = copysignf(erfv, x);
    return 0.5f * v * (1.f + erfv);
}

template<int N> __device__ __forceinline__ void waitcnt_vm() {
    if constexpr (N == 8)      asm volatile("s_waitcnt vmcnt(8)" ::: "memory");
    else if constexpr (N == 6) asm volatile("s_waitcnt vmcnt(6)" ::: "memory");
    else                       asm volatile("s_waitcnt vmcnt(0)" ::: "memory");
}

// ---------------- router: logits, softmax-top2 gates, expert histogram ----------
__global__ void router_kernel(const float* __restrict__ x, const float* __restrict__ Wr,
                              const float* __restrict__ br, int* __restrict__ top_idx,
                              float* __restrict__ gates, int* __restrict__ counts) {
    const int t = blockIdx.x;
    const int lane = threadIdx.x;
    float part[8];
#pragma unroll
    for (int e = 0; e < 8; ++e) part[e] = 0.f;
#pragma unroll
    for (int j = 0; j < 4; ++j) {
        const int d0 = j * 256 + lane * 4;
        const float4 xv = *(const float4*)(x + (size_t)t * DMODEL + d0);
        const float xs[4] = {xv.x, xv.y, xv.z, xv.w};
#pragma unroll
        for (int i = 0; i < 4; ++i) {
            const float4 w0 = *(const float4*)(Wr + (d0 + i) * 8);
            const float4 w1 = *(const float4*)(Wr + (d0 + i) * 8 + 4);
            part[0] += xs[i] * w0.x; part[1] += xs[i] * w0.y;
            part[2] += xs[i] * w0.z; part[3] += xs[i] * w0.w;
            part[4] += xs[i] * w1.x; part[5] += xs[i] * w1.y;
            part[6] += xs[i] * w1.z; part[7] += xs[i] * w1.w;
        }
    }
#pragma unroll
    for (int m = 32; m > 0; m >>= 1)
#pragma unroll
        for (int e = 0; e < 8; ++e) part[e] += __shfl_xor(part[e], m, 64);
    if (lane == 0) {
        float l[8];
#pragma unroll
        for (int e = 0; e < 8; ++e) l[e] = part[e] + br[e];
        int i1 = 0;
#pragma unroll
        for (int e = 1; e < 8; ++e) if (l[e] > l[i1]) i1 = e;   // first-index tiebreak
        int i2 = (i1 == 0) ? 1 : 0;
#pragma unroll
        for (int e = 0; e < 8; ++e) if (e != i1 && l[e] > l[i2]) i2 = e;
        const float e2 = expf(l[i2] - l[i1]);
        const float inv = 1.f / (1.f + e2);
        top_idx[t * 2 + 0] = i1;  gates[t * 2 + 0] = inv;
        top_idx[t * 2 + 1] = i2;  gates[t * 2 + 1] = e2 * inv;
        atomicAdd(&counts[i1], 1);
        atomicAdd(&counts[i2], 1);
    }
}

// ---------------- fused scan + fill (single block; LDS cursors) ------------------
__global__ void fillscan_kernel(const int* __restrict__ top_idx, const int* __restrict__ counts,
                                int* __restrict__ offs, int* __restrict__ rowtoken,
                                int* __restrict__ slotof) {
    __shared__ int lcur[8];
    if (threadIdx.x == 0) {
        int s = 0;
        for (int e = 0; e < 8; ++e) { offs[e] = s; lcur[e] = s; s += counts[e]; }
        offs[8] = s;
    }
    __syncthreads();
    for (int t = threadIdx.x; t < T_TOK; t += 1024) {
#pragma unroll
        for (int k = 0; k < 2; ++k) {
            const int e = top_idx[t * 2 + k];
            const int p = atomicAdd(&lcur[e], 1);
            rowtoken[p] = t;
            slotof[t * 2 + k] = p;
        }
    }
}

// ---------------- gather x rows (fp32 -> bf16) into sorted order -----------------
__global__ void gather_kernel(const float* __restrict__ x, const int* __restrict__ rowtoken,
                              u16* __restrict__ Xg) {
    const int p = blockIdx.x;
    const int t = rowtoken[p];
    const int d = threadIdx.x * 4;
    const float4 v = *(const float4*)(x + (size_t)t * DMODEL + d);
    ushort4 o;
    o.x = f2bf(v.x); o.y = f2bf(v.y); o.z = f2bf(v.z); o.w = f2bf(v.w);
    *(ushort4*)(Xg + (size_t)p * DMODEL + d) = o;
}

// ---------------- transpose + fp32->bf16 weight conversion -----------------------
// src [batch][R][C] f32 -> dst [batch][C][R] bf16
__global__ __launch_bounds__(256) void transpose_convert_kernel(
    const float* __restrict__ src, u16* __restrict__ dst, int R, int C) {
    __shared__ float tile[64][65];
    const size_t base = (size_t)blockIdx.z * R * C;
    const int r0 = blockIdx.y * 64, c0 = blockIdx.x * 64;
    const int tr = threadIdx.x >> 4;
    const int tc4 = (threadIdx.x & 15) * 4;
#pragma unroll
    for (int i = 0; i < 4; ++i) {
        const int r = tr + i * 16;
        const float4 v = *(const float4*)(src + base + (size_t)(r0 + r) * C + c0 + tc4);
        tile[r][tc4 + 0] = v.x; tile[r][tc4 + 1] = v.y;
        tile[r][tc4 + 2] = v.z; tile[r][tc4 + 3] = v.w;
    }
    __syncthreads();
#pragma unroll
    for (int i = 0; i < 4; ++i) {
        const int rr = tr + i * 16;
        ushort4 o;
        o.x = f2bf(tile[tc4 + 0][rr]);
        o.y = f2bf(tile[tc4 + 1][rr]);
        o.z = f2bf(tile[tc4 + 2][rr]);
        o.w = f2bf(tile[tc4 + 3][rr]);
        *(ushort4*)(dst + base + (size_t)(c0 + rr) * R + r0 + tc4) = o;
    }
}

// ---------------- grouped GEMM, 256x256 tile, counted-vmcnt double-buffer --------
// C[p][col] = A[p][k0..k0+64*ksteps) dot B[col][.], per-expert B panels.
// Inner K-loop skeleton identical to round-4/5 verified kernel:
//   waitcnt vmcnt(8) -> s_barrier -> compute -> s_barrier -> stage(t+2).
// T2 both-sides XOR swizzle (bank conflicts measured 0), T5 setprio.
// NEW (round 6): bid decode is (tm0 outer, tn, kh, e inner) so active tiles are
// dispatched FIRST (all 256 CUs concurrently active) and XCD = bid%8 = e pins
// each expert's sub-GEMM to one XCD's L2. Persistent-lite: block loops
// tm = tm0, tm0+GM, ... so worst-case imbalance is covered without dead grid.
template<bool GELU>
__global__ __launch_bounds__(512, 2) void gemm256_kernel(
    const u16* __restrict__ Amat, const int lda,
    const u16* __restrict__ Bmat, const int ldb,
    const float* __restrict__ bias,
    u16* __restrict__ C0, u16* __restrict__ C1, const int ldc,
    const int* __restrict__ offs, const int* __restrict__ counts,
    const int Ntot, const int NT, const int KH, const int ksteps, const int GM) {
    int bid = blockIdx.x;
    const int e  = bid & 7;   bid >>= 3;
    const int kh = bid % KH;  bid /= KH;
    const int tn = bid % NT;  bid /= NT;
    const int tm0 = bid;
    const int cnt = counts[e];
    if (tm0 * 256 >= cnt) return;
    const int pend  = offs[e] + cnt;
    const int nbase = tn * 256;
    const int k0 = kh * (ksteps << 6);
    u16* __restrict__ Cmat = kh ? C1 : C0;

    __shared__ __align__(16) u16 As[2][256 * 64];
    __shared__ __align__(16) u16 Bs[2][256 * 64];

    const int tid = threadIdx.x;
    const int lane = tid & 63, wid = tid >> 6;
    const int wm = (wid >> 2) * 128;
    const int wn = (wid & 3) * 64;
    const int fr = lane & 15, fg = lane >> 4;
    const int rsw = (fr & 7) * 8;            // read-side XOR (elements)

    // stage: 16B chunk c = tid + 512*i -> LDS row (tid>>3)+64*i; global col
    // pre-swizzled so the LDS-linear write lands swizzled data (rule #21).
    const int srow = tid >> 3;
    const int scol = 8 * ((tid & 7) ^ ((tid >> 3) & 7));
    const u16* Bptr = Bmat + (size_t)e * Ntot * ldb
                           + (size_t)(nbase + srow) * ldb + k0 + scol;

    // per-lane bias hoist (4 distinct columns), invariant across tm items
    float bv[4];
#pragma unroll
    for (int n = 0; n < 4; ++n)
        bv[n] = GELU ? bias[e * Ntot + nbase + wn + n * 16 + fr] : 0.f;

    for (int tm = tm0; tm * 256 < cnt; tm += GM) {
        const int pbase = offs[e] + tm * 256;
        const u16* Aptr = Amat + (size_t)(pbase + srow) * lda + k0 + scol;

        f32x4 acc[8][4];
#pragma unroll
        for (int m = 0; m < 8; ++m)
#pragma unroll
            for (int n = 0; n < 4; ++n) acc[m][n] = (f32x4){0.f, 0.f, 0.f, 0.f};

        auto stage = [&](int buf, int ks) {
#pragma unroll
            for (int i = 0; i < 4; ++i)
                __builtin_amdgcn_global_load_lds(
                    (const __attribute__((address_space(1))) void*)(Aptr + ks + (size_t)(64 * i) * lda),
                    (__attribute__((address_space(3))) void*)(&As[buf][(size_t)(tid + 512 * i) * 8]),
                    16, 0, 0);
#pragma unroll
            for (int i = 0; i < 4; ++i)
                __builtin_amdgcn_global_load_lds(
                    (const __attribute__((address_space(1))) void*)(Bptr + ks + (size_t)(64 * i) * ldb),
                    (__attribute__((address_space(3))) void*)(&Bs[buf][(size_t)(tid + 512 * i) * 8]),
                    16, 0, 0);
        };
        auto compute = [&](int buf) {
#pragma unroll
            for (int kc = 0; kc < 2; ++kc) {
                const int col = (kc * 32 + fg * 8) ^ rsw;
                bf16x8 a[8], b[4];
#pragma unroll
                for (int m = 0; m < 8; ++m)
                    a[m] = *(const bf16x8*)(&As[buf][(wm + m * 16 + fr) * 64 + col]);
#pragma unroll
                for (int n = 0; n < 4; ++n)
                    b[n] = *(const bf16x8*)(&Bs[buf][(wn + n * 16 + fr) * 64 + col]);
                __builtin_amdgcn_s_setprio(1);
#pragma unroll
                for (int m = 0; m < 8; ++m)
#pragma unroll
                    for (int n = 0; n < 4; ++n)
                        acc[m][n] = __builtin_amdgcn_mfma_f32_16x16x32_bf16(
                            a[m], b[n], acc[m][n], 0, 0, 0);
                __builtin_amdgcn_s_setprio(0);
            }
        };

        __syncthreads();   // all waves done reading LDS from previous item
        stage(0, 0);
        stage(1, 64);
        const int nk = ksteps;
        for (int t = 0; t < nk; ++t) {
            // own-wave tile-t loads done; barrier publishes all waves' writes
            if (t < nk - 1) waitcnt_vm<8>(); else waitcnt_vm<0>();
            __builtin_amdgcn_s_barrier();
            asm volatile("" ::: "memory");   // ds_reads may not hoist above barrier
            compute(t & 1);
            if (t < nk - 2) {
                asm volatile("" ::: "memory");   // ds_reads may not sink below barrier
                __builtin_amdgcn_s_barrier();    // all waves done reading buf[t&1]
                stage(t & 1, (t + 2) << 6);      // overwrite with tile t+2 (stays in flight)
            }
        }

        // epilogue
#pragma unroll
        for (int m = 0; m < 8; ++m) {
#pragma unroll
            for (int r = 0; r < 4; ++r) {
                const int p = pbase + wm + m * 16 + fg * 4 + r;
                if (p >= pend) continue;
#pragma unroll
                for (int n = 0; n < 4; ++n) {
                    const int col = nbase + wn + n * 16 + fr;
                    float v = acc[m][n][r];
                    if (GELU) v = fast_gelu(v + bv[n]);
                    Cmat[(size_t)p * ldc + col] = f2bf(v);
                }
            }
        }
    }
}

// ------- combine: out[t] = sum_k g_k * (y0[p_k] + y1[p_k] + b2[e_k]) -------------
__global__ void combine_kernel(const u16* __restrict__ ybuf0, const u16* __restrict__ ybuf1,
                               const float* __restrict__ b2,
                               const int* __restrict__ top_idx, const float* __restrict__ gates,
                               const int* __restrict__ slotof, float* __restrict__ out) {
    const int t = blockIdx.x;
    const int d = threadIdx.x * 4;
    const int e0 = top_idx[t * 2 + 0], e1 = top_idx[t * 2 + 1];
    const float g0 = gates[t * 2 + 0], g1 = gates[t * 2 + 1];
    const int p0 = slotof[t * 2 + 0], p1 = slotof[t * 2 + 1];
    const ushort4 ya0 = *(const ushort4*)(ybuf0 + (size_t)p0 * DMODEL + d);
    const ushort4 ya1 = *(const ushort4*)(ybuf1 + (size_t)p0 * DMODEL + d);
    const ushort4 yb0 = *(const ushort4*)(ybuf0 + (size_t)p1 * DMODEL + d);
    const ushort4 yb1 = *(const ushort4*)(ybuf1 + (size_t)p1 * DMODEL + d);
    const float4 ba = *(const float4*)(b2 + e0 * DMODEL + d);
    const float4 bb = *(const float4*)(b2 + e1 * DMODEL + d);
    float4 o;
    o.x = g0 * (bf2f(ya0.x) + bf2f(ya1.x) + ba.x) + g1 * (bf2f(yb0.x) + bf2f(yb1.x) + bb.x);
    o.y = g0 * (bf2f(ya0.y) + bf2f(ya1.y) + ba.y) + g1 * (bf2f(yb0.y) + bf2f(yb1.y) + bb.y);
    o.z = g0 * (bf2f(ya0.z) + bf2f(ya1.z) + ba.z) + g1 * (bf2f(yb0.z) + bf2f(yb1.z) + bb.z);
    o.w = g0 * (bf2f(ya0.w) + bf2f(ya1.w) + ba.w) + g1 * (bf2f(yb0.w) + bf2f(yb1.w) + bb.w);
    *(float4*)(out + (size_t)t * DMODEL + d) = o;
}

extern "C" void kernel_launch(void* const* d_in, const int* in_sizes, int n_in,
                              void* d_out, int out_size, void* d_ws, size_t ws_size,
                              hipStream_t stream) {
    const float* x  = (const float*)d_in[0];
    const float* Wr = (const float*)d_in[1];
    const float* br = (const float*)d_in[2];
    const float* W1 = (const float*)d_in[3];
    const float* b1 = (const float*)d_in[4];
    const float* W2 = (const float*)d_in[5];
    const float* b2 = (const float*)d_in[6];
    float* out = (float*)d_out;

    // workspace carve (all 16B aligned)
    char* w = (char*)d_ws;
    int*   counts   = (int*)(w + 0);          // 32 B
    int*   offs     = (int*)(w + 64);         // 64 B
    int*   top_idx  = (int*)(w + 1024);                   // 32 KB
    float* gates    = (float*)(w + 1024 + 32768);         // 32 KB
    int*   rowtoken = (int*)(w + 1024 + 65536);           // 40 KB reserved
    int*   slotof   = (int*)(w + 1024 + 65536 + 40960);   // 32 KB
    u16*   Xg       = (u16*)(w + 1024 + 65536 + 40960 + 32768);
    u16*   hbuf     = Xg + (size_t)ROWS_PAD * DMODEL;
    u16*   W1T      = hbuf + (size_t)ROWS_PAD * DFF;
    u16*   W2T      = W1T + (size_t)NEXP * DFF * DMODEL;
    u16*   ybuf0    = Xg;    // Xg dead after ffn1  [ROWS_PAD][DMODEL]
    u16*   ybuf1    = W1T;   // W1T dead after ffn1 [ROWS_PAD][DMODEL] (fits: 17MB < 64MB)
    const size_t need = (size_t)(1024 + 65536 + 40960 + 32768)
        + (size_t)ROWS_PAD * DMODEL * 2 + (size_t)ROWS_PAD * DFF * 2
        + (size_t)NEXP * DFF * DMODEL * 4;
    if (ws_size < need) return;  // fail loudly (absmax) rather than corrupt memory

    hipMemsetAsync(d_ws, 0, 64, stream);  // counts

    // weight transpose/convert: W1 [e][1024][4096] -> W1T [e][4096][1024]
    transpose_convert_kernel<<<dim3(64, 16, 8), 256, 0, stream>>>(W1, W1T, DMODEL, DFF);
    // W2 [e][4096][1024] -> W2T [e][1024][4096]
    transpose_convert_kernel<<<dim3(16, 64, 8), 256, 0, stream>>>(W2, W2T, DFF, DMODEL);

    router_kernel<<<T_TOK, 64, 0, stream>>>(x, Wr, br, top_idx, gates, counts);
    fillscan_kernel<<<1, 1024, 0, stream>>>(top_idx, counts, offs, rowtoken, slotof);
    gather_kernel<<<ROWS_TOT, 256, 0, stream>>>(x, rowtoken, Xg);

    // ffn1: h = gelu(Xg @ W1T^T + b1); K=1024 (16 steps), KH=1, GM=6
    // grid = GM(6) x NT(16) x KH(1) x E(8) = 768, active-first dispatch
    gemm256_kernel<true><<<768, 512, 0, stream>>>(
        Xg, DMODEL, W1T, DMODEL, b1, hbuf, nullptr, DFF,
        offs, counts, DFF, 16, 1, 16, 6);
    // ffn2: y = h @ W2T^T; split-K=2 (2048 each, 32 steps), GM=6
    // grid = GM(6) x NT(4) x KH(2) x E(8) = 384
    gemm256_kernel<false><<<384, 512, 0, stream>>>(
        hbuf, DFF, W2T, DFF, nullptr, ybuf0, ybuf1, DMODEL,
        offs, counts, DMODEL, 4, 2, 32, 6);
    // combine: one block per token
    combine_kernel<<<T_TOK, 256, 0, stream>>>(ybuf0, ybuf1, b2, top_idx, gates, slotof, out);
}

// Round 7
// 441.156 us; speedup vs baseline: 1.5108x; 1.0627x over previous
//
#include <hip/hip_runtime.h>
#include <hip/hip_bf16.h>

#define T_TOK 4096
#define DMODEL 1024
#define DFF 4096
#define NEXP 8
#define ROWS_TOT 8192      // T_TOK * TOPK, fixed
#define ROWS_PAD 8448      // + 256 pad rows for BM=256 tile overrun

typedef __bf16 bf16x8 __attribute__((ext_vector_type(8)));
typedef float f32x4 __attribute__((ext_vector_type(4)));
typedef unsigned short u16;

template<int V> struct ic { static constexpr int value = V; };

__device__ __forceinline__ u16 f2bf(float f) {
    __hip_bfloat16 b = __float2bfloat16(f);
    return __builtin_bit_cast(u16, b);
}
__device__ __forceinline__ float bf2f(u16 u) {
    unsigned v = (unsigned)u << 16;
    return __builtin_bit_cast(float, v);
}

// exact-erf GELU via Abramowitz-Stegun 7.1.26 (|eps|<=1.5e-7 << bf16 rounding of h)
__device__ __forceinline__ float fast_gelu(float v) {
    const float x = v * 0.70710678118654752f;
    const float ax = fabsf(x);
    const float t = 1.f / fmaf(0.3275911f, ax, 1.f);
    float p = fmaf(1.061405429f, t, -1.453152027f);
    p = fmaf(p, t, 1.421413741f);
    p = fmaf(p, t, -0.284496736f);
    p = fmaf(p, t, 0.254829592f);
    p *= t;
    const float e = __expf(-ax * ax);
    float erfv = fmaf(-p, e, 1.f);
    erfv = copysignf(erfv, x);
    return 0.5f * v * (1.f + erfv);
}

// ---------------- router: logits, softmax-top2 gates, expert histogram ----------
__global__ void router_kernel(const float* __restrict__ x, const float* __restrict__ Wr,
                              const float* __restrict__ br, int* __restrict__ top_idx,
                              float* __restrict__ gates, int* __restrict__ counts) {
    const int t = blockIdx.x;
    const int lane = threadIdx.x;
    float part[8];
#pragma unroll
    for (int e = 0; e < 8; ++e) part[e] = 0.f;
#pragma unroll
    for (int j = 0; j < 4; ++j) {
        const int d0 = j * 256 + lane * 4;
        const float4 xv = *(const float4*)(x + (size_t)t * DMODEL + d0);
        const float xs[4] = {xv.x, xv.y, xv.z, xv.w};
#pragma unroll
        for (int i = 0; i < 4; ++i) {
            const float4 w0 = *(const float4*)(Wr + (d0 + i) * 8);
            const float4 w1 = *(const float4*)(Wr + (d0 + i) * 8 + 4);
            part[0] += xs[i] * w0.x; part[1] += xs[i] * w0.y;
            part[2] += xs[i] * w0.z; part[3] += xs[i] * w0.w;
            part[4] += xs[i] * w1.x; part[5] += xs[i] * w1.y;
            part[6] += xs[i] * w1.z; part[7] += xs[i] * w1.w;
        }
    }
#pragma unroll
    for (int m = 32; m > 0; m >>= 1)
#pragma unroll
        for (int e = 0; e < 8; ++e) part[e] += __shfl_xor(part[e], m, 64);
    if (lane == 0) {
        float l[8];
#pragma unroll
        for (int e = 0; e < 8; ++e) l[e] = part[e] + br[e];
        int i1 = 0;
#pragma unroll
        for (int e = 1; e < 8; ++e) if (l[e] > l[i1]) i1 = e;   // first-index tiebreak
        int i2 = (i1 == 0) ? 1 : 0;
#pragma unroll
        for (int e = 0; e < 8; ++e) if (e != i1 && l[e] > l[i2]) i2 = e;
        const float e2 = expf(l[i2] - l[i1]);
        const float inv = 1.f / (1.f + e2);
        top_idx[t * 2 + 0] = i1;  gates[t * 2 + 0] = inv;
        top_idx[t * 2 + 1] = i2;  gates[t * 2 + 1] = e2 * inv;
        atomicAdd(&counts[i1], 1);
        atomicAdd(&counts[i2], 1);
    }
}

// ---------------- fused scan + fill (single block; LDS cursors) ------------------
__global__ void fillscan_kernel(const int* __restrict__ top_idx, const int* __restrict__ counts,
                                int* __restrict__ offs, int* __restrict__ rowtoken,
                                int* __restrict__ slotof) {
    __shared__ int lcur[8];
    if (threadIdx.x == 0) {
        int s = 0;
        for (int e = 0; e < 8; ++e) { offs[e] = s; lcur[e] = s; s += counts[e]; }
        offs[8] = s;
    }
    __syncthreads();
    for (int t = threadIdx.x; t < T_TOK; t += 1024) {
#pragma unroll
        for (int k = 0; k < 2; ++k) {
            const int e = top_idx[t * 2 + k];
            const int p = atomicAdd(&lcur[e], 1);
            rowtoken[p] = t;
            slotof[t * 2 + k] = p;
        }
    }
}

// ---------------- gather x rows (fp32 -> bf16) into sorted order -----------------
__global__ void gather_kernel(const float* __restrict__ x, const int* __restrict__ rowtoken,
                              u16* __restrict__ Xg) {
    const int p = blockIdx.x;
    const int t = rowtoken[p];
    const int d = threadIdx.x * 4;
    const float4 v = *(const float4*)(x + (size_t)t * DMODEL + d);
    ushort4 o;
    o.x = f2bf(v.x); o.y = f2bf(v.y); o.z = f2bf(v.z); o.w = f2bf(v.w);
    *(ushort4*)(Xg + (size_t)p * DMODEL + d) = o;
}

// ---------------- transpose + fp32->bf16 weight conversion -----------------------
// src [batch][R][C] f32 -> dst [batch][C][R] bf16
__global__ __launch_bounds__(256) void transpose_convert_kernel(
    const float* __restrict__ src, u16* __restrict__ dst, int R, int C) {
    __shared__ float tile[64][65];
    const size_t base = (size_t)blockIdx.z * R * C;
    const int r0 = blockIdx.y * 64, c0 = blockIdx.x * 64;
    const int tr = threadIdx.x >> 4;
    const int tc4 = (threadIdx.x & 15) * 4;
#pragma unroll
    for (int i = 0; i < 4; ++i) {
        const int r = tr + i * 16;
        const float4 v = *(const float4*)(src + base + (size_t)(r0 + r) * C + c0 + tc4);
        tile[r][tc4 + 0] = v.x; tile[r][tc4 + 1] = v.y;
        tile[r][tc4 + 2] = v.z; tile[r][tc4 + 3] = v.w;
    }
    __syncthreads();
#pragma unroll
    for (int i = 0; i < 4; ++i) {
        const int rr = tr + i * 16;
        ushort4 o;
        o.x = f2bf(tile[tc4 + 0][rr]);
        o.y = f2bf(tile[tc4 + 1][rr]);
        o.z = f2bf(tile[tc4 + 2][rr]);
        o.w = f2bf(tile[tc4 + 3][rr]);
        *(ushort4*)(dst + base + (size_t)(c0 + rr) * R + r0 + tc4) = o;
    }
}

// ---------------- grouped GEMM, 256x256 tile, 8-phase counted-vmcnt pipeline -----
// Per K-tile (BK=64): 4 phases = output quadrants (QM,QN); 8 waves tile each
// 128x128 quadrant as 2Mx4N (wave-phase subtile 64x32, 16 MFMA). A-half frags
// re-read per QM change (phases 1,3); B-half frag sets held in registers (read
// phases 1,2). Phase order (0,0),(0,1),(1,1),(1,0) retires LDS halves early:
//   A0,B0 dead after ph1; B1 after ph2; A1 after ph3.
// Staging stream: 1 half-tile per phase (2 gload_lds), order [A0,B0,B1,A1] of
// tile t+2, each into a slot dead >=1 phase earlier; min stage->use gap = 6
// phases. vmcnt(6) at every phase start guarantees gap-4 stages landed; loads
// are never drained to 0 inside the loop (T4). One barrier per phase: it both
// publishes staged halves (with the vmcnt) and protects slot overwrite (last
// reader's lgkmcnt-complete ds_reads precede its barrier arrival).
// T2 both-sides XOR swizzle (bank conflicts measured 0), T5 setprio.
template<bool GELU>
__global__ __launch_bounds__(512, 2) void gemm8ph_kernel(
    const u16* __restrict__ Amat, const int lda,
    const u16* __restrict__ Bmat, const int ldb,
    const float* __restrict__ bias,
    u16* __restrict__ C0, u16* __restrict__ C1, const int ldc,
    const int* __restrict__ offs, const int* __restrict__ counts,
    const int Ntot, const int NT, const int KH, const int J, const int GM) {
    int bid = blockIdx.x;
    const int e  = bid & 7;   bid >>= 3;
    const int kh = bid % KH;  bid /= KH;
    const int tn = bid % NT;  bid /= NT;
    const int tm0 = bid;
    const int cnt = counts[e];
    if (tm0 * 256 >= cnt) return;
    const int pend  = offs[e] + cnt;
    const int nbase = tn * 256;
    const int k0 = kh * (J << 6);
    u16* __restrict__ Cmat = kh ? C1 : C0;

    __shared__ __align__(16) u16 As[2][2][128 * 64];
    __shared__ __align__(16) u16 Bs[2][2][128 * 64];

    const int tid = threadIdx.x;
    const int lane = tid & 63, wid = tid >> 6;
    const int wr = (wid >> 2) * 64;      // row offset within 128-row quadrant half
    const int wc = (wid & 3) * 32;       // col offset within 128-col quadrant half
    const int fr = lane & 15, fg = lane >> 4;
    const int rsw = (fr & 7) * 8;        // read-side XOR (elements)

    // stage: 16B chunk c = tid + 512*i -> LDS row (tid>>3)+64*i of a 128x64 half;
    // global col pre-swizzled so the LDS-linear write lands swizzled data.
    const int srow = tid >> 3;
    const int scol = 8 * ((tid & 7) ^ ((tid >> 3) & 7));
    const u16* Bpt = Bmat + (size_t)e * Ntot * ldb
                          + (size_t)(nbase + srow) * ldb + k0 + scol;

    // per-lane bias hoist (4 distinct columns), invariant across tm items
    float bv[2][2];
#pragma unroll
    for (int q = 0; q < 2; ++q)
#pragma unroll
        for (int n = 0; n < 2; ++n)
            bv[q][n] = GELU ? bias[e * Ntot + nbase + q * 128 + wc + n * 16 + fr] : 0.f;

    for (int tm = tm0; tm * 256 < cnt; tm += GM) {
        const int pbase = offs[e] + tm * 256;
        const u16* Apt = Amat + (size_t)(pbase + srow) * lda + k0 + scol;

        f32x4 acc[2][2][4][2];
#pragma unroll
        for (int qm = 0; qm < 2; ++qm)
#pragma unroll
            for (int qn = 0; qn < 2; ++qn)
#pragma unroll
                for (int m = 0; m < 4; ++m)
#pragma unroll
                    for (int n = 0; n < 2; ++n)
                        acc[qm][qn][m][n] = (f32x4){0.f, 0.f, 0.f, 0.f};

        bf16x8 aA[4][2];        // current A-half fragments (reloaded on QM change)
        bf16x8 bB[2][2][2];     // both B-half fragment sets [half][n][kc]

        auto stageHalf = [&](int tile, int which) {
            const int b = tile & 1;
            const int kofs = tile << 6;
            if ((which & 1) == 0) {            // A-half h = which>>1
                const int h = which >> 1;
#pragma unroll
                for (int i = 0; i < 2; ++i)
                    __builtin_amdgcn_global_load_lds(
                        (const __attribute__((address_space(1))) void*)
                            (Apt + kofs + (size_t)(h * 128 + 64 * i) * lda),
                        (__attribute__((address_space(3))) void*)(&As[b][h][(size_t)(tid + 512 * i) * 8]),
                        16, 0, 0);
            } else {                           // B-half: which 1->h0, 3->h1
                const int h = which >> 1;
#pragma unroll
                for (int i = 0; i < 2; ++i)
                    __builtin_amdgcn_global_load_lds(
                        (const __attribute__((address_space(1))) void*)
                            (Bpt + kofs + (size_t)(h * 128 + 64 * i) * ldb),
                        (__attribute__((address_space(3))) void*)(&Bs[b][h][(size_t)(tid + 512 * i) * 8]),
                        16, 0, 0);
            }
        };

        __syncthreads();   // all waves done reading LDS from previous item
#pragma unroll
        for (int q = 0; q < 4; ++q) stageHalf(0, q);
#pragma unroll
        for (int q = 0; q < 4; ++q) stageHalf(1, q);

        int phi = 0;
        const int smax = 4 * (J - 2);
        auto phase = [&](auto BBc, auto QMc, auto QNc, auto RDAc, auto RDBc) {
            constexpr int BB  = decltype(BBc)::value;
            constexpr int QM  = decltype(QMc)::value;
            constexpr int QN  = decltype(QNc)::value;
            constexpr int RDA = decltype(RDAc)::value;
            constexpr int RDB = decltype(RDBc)::value;
            asm volatile("s_waitcnt vmcnt(6)" ::: "memory");
            __builtin_amdgcn_s_barrier();
            asm volatile("" ::: "memory");
            if constexpr (RDA) {
#pragma unroll
                for (int m = 0; m < 4; ++m)
#pragma unroll
                    for (int kc = 0; kc < 2; ++kc)
                        aA[m][kc] = *(const bf16x8*)(&As[BB][QM][
                            (wr + m * 16 + fr) * 64 + ((kc * 32 + fg * 8) ^ rsw)]);
            }
            if constexpr (RDB >= 0) {
#pragma unroll
                for (int n = 0; n < 2; ++n)
#pragma unroll
                    for (int kc = 0; kc < 2; ++kc)
                        bB[RDB][n][kc] = *(const bf16x8*)(&Bs[BB][RDB][
                            (wc + n * 16 + fr) * 64 + ((kc * 32 + fg * 8) ^ rsw)]);
            }
            {
                const int s = phi - 1;   // stream starts at the 2nd phase overall
                if (s >= 0 && s < smax) {
                    constexpr int sord[4] = {0, 1, 3, 2};   // A0,B0,B1,A1
                    stageHalf(2 + (s >> 2), sord[s & 3]);
                }
                ++phi;
            }
            __builtin_amdgcn_s_setprio(1);
#pragma unroll
            for (int kc = 0; kc < 2; ++kc)
#pragma unroll
                for (int m = 0; m < 4; ++m)
#pragma unroll
                    for (int n = 0; n < 2; ++n)
                        acc[QM][QN][m][n] = __builtin_amdgcn_mfma_f32_16x16x32_bf16(
                            aA[m][kc], bB[QN][n][kc], acc[QM][QN][m][n], 0, 0, 0);
            __builtin_amdgcn_s_setprio(0);
        };

        const int niter = J >> 1;
        for (int it = 0; it < niter; ++it) {
            phase(ic<0>{}, ic<0>{}, ic<0>{}, ic<1>{}, ic<0>{});   // ph1: read A0,B0
            phase(ic<0>{}, ic<0>{}, ic<1>{}, ic<0>{}, ic<1>{});   // ph2: read B1
            phase(ic<0>{}, ic<1>{}, ic<1>{}, ic<1>{}, ic<-1>{});  // ph3: read A1
            phase(ic<0>{}, ic<1>{}, ic<0>{}, ic<0>{}, ic<-1>{});  // ph4: regs only
            phase(ic<1>{}, ic<0>{}, ic<0>{}, ic<1>{}, ic<0>{});   // ph5
            phase(ic<1>{}, ic<0>{}, ic<1>{}, ic<0>{}, ic<1>{});   // ph6
            phase(ic<1>{}, ic<1>{}, ic<1>{}, ic<1>{}, ic<-1>{});  // ph7
            phase(ic<1>{}, ic<1>{}, ic<0>{}, ic<0>{}, ic<-1>{});  // ph8
        }

        // epilogue
#pragma unroll
        for (int qm = 0; qm < 2; ++qm) {
#pragma unroll
            for (int m = 0; m < 4; ++m) {
#pragma unroll
                for (int r = 0; r < 4; ++r) {
                    const int p = pbase + qm * 128 + wr + m * 16 + fg * 4 + r;
                    if (p >= pend) continue;
#pragma unroll
                    for (int qn = 0; qn < 2; ++qn) {
#pragma unroll
                        for (int n = 0; n < 2; ++n) {
                            const int col = nbase + qn * 128 + wc + n * 16 + fr;
                            float v = acc[qm][qn][m][n][r];
                            if (GELU) v = fast_gelu(v + bv[qn][n]);
                            Cmat[(size_t)p * ldc + col] = f2bf(v);
                        }
                    }
                }
            }
        }
    }
}

// ------- combine: out[t] = sum_k g_k * (y0[p_k] + y1[p_k] + b2[e_k]) -------------
__global__ void combine_kernel(const u16* __restrict__ ybuf0, const u16* __restrict__ ybuf1,
                               const float* __restrict__ b2,
                               const int* __restrict__ top_idx, const float* __restrict__ gates,
                               const int* __restrict__ slotof, float* __restrict__ out) {
    const int t = blockIdx.x;
    const int d = threadIdx.x * 4;
    const int e0 = top_idx[t * 2 + 0], e1 = top_idx[t * 2 + 1];
    const float g0 = gates[t * 2 + 0], g1 = gates[t * 2 + 1];
    const int p0 = slotof[t * 2 + 0], p1 = slotof[t * 2 + 1];
    const ushort4 ya0 = *(const ushort4*)(ybuf0 + (size_t)p0 * DMODEL + d);
    const ushort4 ya1 = *(const ushort4*)(ybuf1 + (size_t)p0 * DMODEL + d);
    const ushort4 yb0 = *(const ushort4*)(ybuf0 + (size_t)p1 * DMODEL + d);
    const ushort4 yb1 = *(const ushort4*)(ybuf1 + (size_t)p1 * DMODEL + d);
    const float4 ba = *(const float4*)(b2 + e0 * DMODEL + d);
    const float4 bb = *(const float4*)(b2 + e1 * DMODEL + d);
    float4 o;
    o.x = g0 * (bf2f(ya0.x) + bf2f(ya1.x) + ba.x) + g1 * (bf2f(yb0.x) + bf2f(yb1.x) + bb.x);
    o.y = g0 * (bf2f(ya0.y) + bf2f(ya1.y) + ba.y) + g1 * (bf2f(yb0.y) + bf2f(yb1.y) + bb.y);
    o.z = g0 * (bf2f(ya0.z) + bf2f(ya1.z) + ba.z) + g1 * (bf2f(yb0.z) + bf2f(yb1.z) + bb.z);
    o.w = g0 * (bf2f(ya0.w) + bf2f(ya1.w) + ba.w) + g1 * (bf2f(yb0.w) + bf2f(yb1.w) + bb.w);
    *(float4*)(out + (size_t)t * DMODEL + d) = o;
}

extern "C" void kernel_launch(void* const* d_in, const int* in_sizes, int n_in,
                              void* d_out, int out_size, void* d_ws, size_t ws_size,
                              hipStream_t stream) {
    const float* x  = (const float*)d_in[0];
    const float* Wr = (const float*)d_in[1];
    const float* br = (const float*)d_in[2];
    const float* W1 = (const float*)d_in[3];
    const float* b1 = (const float*)d_in[4];
    const float* W2 = (const float*)d_in[5];
    const float* b2 = (const float*)d_in[6];
    float* out = (float*)d_out;

    // workspace carve (all 16B aligned)
    char* w = (char*)d_ws;
    int*   counts   = (int*)(w + 0);          // 32 B
    int*   offs     = (int*)(w + 64);         // 64 B
    int*   top_idx  = (int*)(w + 1024);                   // 32 KB
    float* gates    = (float*)(w + 1024 + 32768);         // 32 KB
    int*   rowtoken = (int*)(w + 1024 + 65536);           // 40 KB reserved
    int*   slotof   = (int*)(w + 1024 + 65536 + 40960);   // 32 KB
    u16*   Xg       = (u16*)(w + 1024 + 65536 + 40960 + 32768);
    u16*   hbuf     = Xg + (size_t)ROWS_PAD * DMODEL;
    u16*   W1T      = hbuf + (size_t)ROWS_PAD * DFF;
    u16*   W2T      = W1T + (size_t)NEXP * DFF * DMODEL;
    u16*   ybuf0    = Xg;    // Xg dead after ffn1  [ROWS_PAD][DMODEL]
    u16*   ybuf1    = W1T;   // W1T dead after ffn1 [ROWS_PAD][DMODEL] (fits: 17MB < 64MB)
    const size_t need = (size_t)(1024 + 65536 + 40960 + 32768)
        + (size_t)ROWS_PAD * DMODEL * 2 + (size_t)ROWS_PAD * DFF * 2
        + (size_t)NEXP * DFF * DMODEL * 4;
    if (ws_size < need) return;  // fail loudly (absmax) rather than corrupt memory

    hipMemsetAsync(d_ws, 0, 64, stream);  // counts

    // weight transpose/convert: W1 [e][1024][4096] -> W1T [e][4096][1024]
    transpose_convert_kernel<<<dim3(64, 16, 8), 256, 0, stream>>>(W1, W1T, DMODEL, DFF);
    // W2 [e][4096][1024] -> W2T [e][1024][4096]
    transpose_convert_kernel<<<dim3(16, 64, 8), 256, 0, stream>>>(W2, W2T, DFF, DMODEL);

    router_kernel<<<T_TOK, 64, 0, stream>>>(x, Wr, br, top_idx, gates, counts);
    fillscan_kernel<<<1, 1024, 0, stream>>>(top_idx, counts, offs, rowtoken, slotof);
    gather_kernel<<<ROWS_TOT, 256, 0, stream>>>(x, rowtoken, Xg);

    // ffn1: h = gelu(Xg @ W1T^T + b1); J=16 K-tiles, KH=1, GM=6
    // grid = GM(6) x NT(16) x KH(1) x E(8) = 768, active-first, e-inner XCD pin
    gemm8ph_kernel<true><<<768, 512, 0, stream>>>(
        Xg, DMODEL, W1T, DMODEL, b1, hbuf, nullptr, DFF,
        offs, counts, DFF, 16, 1, 16, 6);
    // ffn2: y = h @ W2T^T; split-K=2 (J=32 K-tiles each), GM=6
    // grid = GM(6) x NT(4) x KH(2) x E(8) = 384
    gemm8ph_kernel<false><<<384, 512, 0, stream>>>(
        hbuf, DFF, W2T, DFF, nullptr, ybuf0, ybuf1, DMODEL,
        offs, counts, DMODEL, 4, 2, 32, 6);
    // combine: one block per token
    combine_kernel<<<T_TOK, 256, 0, stream>>>(ybuf0, ybuf1, b2, top_idx, gates, slotof, out);
}